// Round 4
// baseline (456.853 us; speedup 1.0000x reference)
//
#include <hip/hip_runtime.h>
#include <stdint.h>

// ============================================================================
// ConcreteSelect: Y[b,s] = X[b, argmax_d(logits[s,d] + gumbel(key=42)[s,d])]
// Gumbel-softmax hard=True forward == one-hot column gather of X.
// PRNG: JAX threefry2x32, partitionable mode: x=(hi32(i),lo32(i)), bits=y0^y1.
// Bit-exact (absmax 0.0, rounds 1-3).
//
// R4: random gather (2.3 TB/s effective on scattered 128B lines) replaced by
// a sequential STREAM of X (coalesced float4, ~6.3 TB/s + L3-warm from the
// harness's X restore). Each block builds a col->s chain map in LDS
// (atomicExch; duplicate columns chained via next[]), scans 8 rows (one per
// wave), stages hits in LDS, flushes Y coalesced.
// ============================================================================

#define S_ROWS 256
#define D_COLS 10000
#define B_ROWS 8192

__device__ __forceinline__ void threefry2x32(uint32_t& x0, uint32_t& x1) {
  const uint32_t k0 = 0u;
  const uint32_t k1 = 42u;
  const uint32_t k2 = 0x1BD11BDAu ^ k0 ^ k1;
  x0 += k0; x1 += k1;
#define TFR(r) { x0 += x1; x1 = (x1 << (r)) | (x1 >> (32 - (r))); x1 ^= x0; }
  TFR(13) TFR(15) TFR(26) TFR(6)   x0 += k1; x1 += k2 + 1u;
  TFR(17) TFR(29) TFR(16) TFR(24)  x0 += k2; x1 += k0 + 2u;
  TFR(13) TFR(15) TFR(26) TFR(6)   x0 += k0; x1 += k1 + 3u;
  TFR(17) TFR(29) TFR(16) TFR(24)  x0 += k1; x1 += k2 + 4u;
  TFR(13) TFR(15) TFR(26) TFR(6)   x0 += k2; x1 += k0 + 5u;
#undef TFR
}

__device__ __forceinline__ uint32_t jax_random_bits(uint32_t i) {
  uint32_t x0 = 0u, x1 = i;
  threefry2x32(x0, x1);
  return x0 ^ x1;
}

__device__ __forceinline__ float uniform_from_bits(uint32_t bits) {
  uint32_t fb = (bits >> 9) | 0x3f800000u;     // [1,2)
  float u = __uint_as_float(fb) - 1.0f;        // [0,1)
  if (u <= 0.0f) u = 1.17549435e-38f;          // max(tiny, u)
  return u;
}

__device__ __forceinline__ float gumbel_f(uint32_t bits) {
  float u  = uniform_from_bits(bits);
  float nl = -logf(u);
  return -logf(nl);
}

__device__ __forceinline__ double gumbel_d(uint32_t bits) {
  float u = uniform_from_bits(bits);
  double lu = log((double)u);
  return -log(-lu);
}

#define ARGMAX_THREADS 1024
#define CAND_MAX 64

__global__ __launch_bounds__(ARGMAX_THREADS)
void argmax_gumbel_kernel(const float* __restrict__ logits, int* __restrict__ idx_out) {
  const int s   = blockIdx.x;      // 0..255
  const int tid = threadIdx.x;     // 0..1023
  const int base = s * D_COLS;

  __shared__ float zbuf[D_COLS];                 // 40 KB
  __shared__ float sv[ARGMAX_THREADS];           // 4 KB
  __shared__ int   si[ARGMAX_THREADS];           // 4 KB
  __shared__ int   n_cand;
  __shared__ int   cand[CAND_MAX];

  if (tid == 0) n_cand = 0;

  float best = -1.0e30f;
  int   bi   = 0;
  for (int d = tid; d < D_COLS; d += ARGMAX_THREADS) {
    uint32_t bits = jax_random_bits((uint32_t)(base + d));
    float z = logits[base + d] + gumbel_f(bits);
    zbuf[d] = z;
    if (z > best) { best = z; bi = d; }
  }
  sv[tid] = best; si[tid] = bi;
  __syncthreads();
  for (int off = ARGMAX_THREADS / 2; off > 0; off >>= 1) {
    if (tid < off) {
      float ov = sv[tid + off]; int oi = si[tid + off];
      if (ov > sv[tid] || (ov == sv[tid] && oi < si[tid])) { sv[tid] = ov; si[tid] = oi; }
    }
    __syncthreads();
  }

  // Double precision decides among all columns within EPS of the float max.
  const float thresh = sv[0] - 1.0e-3f;
  for (int d = tid; d < D_COLS; d += ARGMAX_THREADS) {
    if (zbuf[d] >= thresh) {
      int pos = atomicAdd(&n_cand, 1);
      if (pos < CAND_MAX) cand[pos] = d;
    }
  }
  __syncthreads();

  if (tid == 0) {
    int    nc   = n_cand < CAND_MAX ? n_cand : CAND_MAX;
    double bz   = -1.0e300;
    int    bidx = 0x7fffffff;
    for (int i = 0; i < nc; ++i) {
      int d = cand[i];
      double z = (double)logits[base + d] + gumbel_d(jax_random_bits((uint32_t)(base + d)));
      if (z > bz || (z == bz && d < bidx)) { bz = z; bidx = d; }
    }
    idx_out[s] = bidx;
  }
}

// --------------------------------------------------------------------------
// Streaming gather: block = 512 threads = 8 waves, wave w scans row b0+w.
// LDS: head[10000] int (col -> first s, -1 if unselected), next[256] chain,
// yrow[8][256] staging. X read coalesced float4; Y flushed coalesced.
// --------------------------------------------------------------------------
#define GATHER_THREADS 512
#define GATHER_ROWS 8
#define ROW_F4 (D_COLS / 4)   // 2500

__global__ __launch_bounds__(GATHER_THREADS)
void stream_gather_kernel(const float* __restrict__ X,
                          const int* __restrict__ idx,
                          float* __restrict__ Y) {
  __shared__ int   head[D_COLS];                     // 40 KB
  __shared__ int   nxt[S_ROWS];                      // 1 KB
  __shared__ float yrow[GATHER_ROWS * S_ROWS];       // 8 KB
  const int tid = threadIdx.x;

  for (int i = tid; i < D_COLS; i += GATHER_THREADS) head[i] = -1;
  __syncthreads();
  if (tid < S_ROWS) {
    int c = idx[tid];                                 // L2-hot broadcast
    nxt[tid] = atomicExch(&head[c], tid);             // dup columns -> chain
  }
  __syncthreads();

  const int wave = tid >> 6;                          // 0..7
  const int lane = tid & 63;
  const long b   = (long)blockIdx.x * GATHER_ROWS + wave;
  const float4* __restrict__ xrow  = (const float4*)(X + b * D_COLS);
  const int4*   __restrict__ head4 = (const int4*)head;
  float* yw = &yrow[wave * S_ROWS];

#define PROC(vv, hh)                                                  \
  {                                                                   \
    if ((hh).x >= 0) { int s=(hh).x; do { yw[s]=(vv).x; s=nxt[s]; } while (s>=0); } \
    if ((hh).y >= 0) { int s=(hh).y; do { yw[s]=(vv).y; s=nxt[s]; } while (s>=0); } \
    if ((hh).z >= 0) { int s=(hh).z; do { yw[s]=(vv).z; s=nxt[s]; } while (s>=0); } \
    if ((hh).w >= 0) { int s=(hh).w; do { yw[s]=(vv).w; s=nxt[s]; } while (s>=0); } \
  }

  int i = lane;
  for (; i + 64 < ROW_F4; i += 128) {                 // 2-deep: 2 loads in flight
    float4 v0 = xrow[i];
    float4 v1 = xrow[i + 64];
    int4   h0 = head4[i];
    int4   h1 = head4[i + 64];
    PROC(v0, h0)
    PROC(v1, h1)
  }
  for (; i < ROW_F4; i += 64) {
    float4 v = xrow[i];
    int4   h = head4[i];
    PROC(v, h)
  }
#undef PROC

  __syncthreads();
  const long o0 = (long)blockIdx.x * GATHER_ROWS * S_ROWS;
  for (int k = tid; k < GATHER_ROWS * S_ROWS; k += GATHER_THREADS)
    Y[o0 + k] = yrow[k];                              // coalesced flush
}

extern "C" void kernel_launch(void* const* d_in, const int* in_sizes, int n_in,
                              void* d_out, int out_size, void* d_ws, size_t ws_size,
                              hipStream_t stream) {
  const float* X      = (const float*)d_in[0];   // [8192, 10000] fp32
  const float* logits = (const float*)d_in[1];   // [256, 10000] fp32
  float*       Y      = (float*)d_out;           // [8192, 256] fp32
  int*         idx    = (int*)d_ws;              // 256 ints scratch

  argmax_gumbel_kernel<<<S_ROWS, ARGMAX_THREADS, 0, stream>>>(logits, idx);
  stream_gather_kernel<<<B_ROWS / GATHER_ROWS, GATHER_THREADS, 0, stream>>>(X, idx, Y);
}

// Round 5
// 422.547 us; speedup vs baseline: 1.0812x; 1.0812x over previous
//
#include <hip/hip_runtime.h>
#include <stdint.h>

// ============================================================================
// ConcreteSelect: Y[b,s] = X[b, argmax_d(logits[s,d] + gumbel(key=42)[s,d])]
// Gumbel-softmax hard=True forward == one-hot column gather of X.
// PRNG: JAX threefry2x32, partitionable mode: x=(hi32(i),lo32(i)), bits=y0^y1.
// Bit-exact (absmax 0.0, rounds 1-4).
//
// R5: revert R4's streaming scan (regressed: ~120us vs ~80us random gather).
// Back to R3 random-gather structure, plus ADDRESS-SORTED requests: a tiny
// rank-sort kernel orders the 256 selected columns ascending; gather thread t
// loads the t-th smallest column so each wave issues ascending addresses
// (DRAM open-page locality). Store scatters within the row's 1KB span to
// restore original s order (merged in L2).
// ============================================================================

#define S_ROWS 256
#define D_COLS 10000
#define B_ROWS 8192

__device__ __forceinline__ void threefry2x32(uint32_t& x0, uint32_t& x1) {
  const uint32_t k0 = 0u;
  const uint32_t k1 = 42u;
  const uint32_t k2 = 0x1BD11BDAu ^ k0 ^ k1;
  x0 += k0; x1 += k1;
#define TFR(r) { x0 += x1; x1 = (x1 << (r)) | (x1 >> (32 - (r))); x1 ^= x0; }
  TFR(13) TFR(15) TFR(26) TFR(6)   x0 += k1; x1 += k2 + 1u;
  TFR(17) TFR(29) TFR(16) TFR(24)  x0 += k2; x1 += k0 + 2u;
  TFR(13) TFR(15) TFR(26) TFR(6)   x0 += k0; x1 += k1 + 3u;
  TFR(17) TFR(29) TFR(16) TFR(24)  x0 += k1; x1 += k2 + 4u;
  TFR(13) TFR(15) TFR(26) TFR(6)   x0 += k2; x1 += k0 + 5u;
#undef TFR
}

__device__ __forceinline__ uint32_t jax_random_bits(uint32_t i) {
  uint32_t x0 = 0u, x1 = i;
  threefry2x32(x0, x1);
  return x0 ^ x1;
}

__device__ __forceinline__ float uniform_from_bits(uint32_t bits) {
  uint32_t fb = (bits >> 9) | 0x3f800000u;     // [1,2)
  float u = __uint_as_float(fb) - 1.0f;        // [0,1)
  if (u <= 0.0f) u = 1.17549435e-38f;          // max(tiny, u)
  return u;
}

__device__ __forceinline__ float gumbel_f(uint32_t bits) {
  float u  = uniform_from_bits(bits);
  float nl = -logf(u);
  return -logf(nl);
}

__device__ __forceinline__ double gumbel_d(uint32_t bits) {
  float u = uniform_from_bits(bits);
  double lu = log((double)u);
  return -log(-lu);
}

#define ARGMAX_THREADS 1024
#define CAND_MAX 64

__global__ __launch_bounds__(ARGMAX_THREADS)
void argmax_gumbel_kernel(const float* __restrict__ logits, int* __restrict__ idx_out) {
  const int s   = blockIdx.x;      // 0..255
  const int tid = threadIdx.x;     // 0..1023
  const int base = s * D_COLS;

  __shared__ float zbuf[D_COLS];                 // 40 KB
  __shared__ float sv[ARGMAX_THREADS];           // 4 KB
  __shared__ int   si[ARGMAX_THREADS];           // 4 KB
  __shared__ int   n_cand;
  __shared__ int   cand[CAND_MAX];

  if (tid == 0) n_cand = 0;

  float best = -1.0e30f;
  int   bi   = 0;
  for (int d = tid; d < D_COLS; d += ARGMAX_THREADS) {
    uint32_t bits = jax_random_bits((uint32_t)(base + d));
    float z = logits[base + d] + gumbel_f(bits);
    zbuf[d] = z;
    if (z > best) { best = z; bi = d; }
  }
  sv[tid] = best; si[tid] = bi;
  __syncthreads();
  for (int off = ARGMAX_THREADS / 2; off > 0; off >>= 1) {
    if (tid < off) {
      float ov = sv[tid + off]; int oi = si[tid + off];
      if (ov > sv[tid] || (ov == sv[tid] && oi < si[tid])) { sv[tid] = ov; si[tid] = oi; }
    }
    __syncthreads();
  }

  // Double precision decides among all columns within EPS of the float max.
  const float thresh = sv[0] - 1.0e-3f;
  for (int d = tid; d < D_COLS; d += ARGMAX_THREADS) {
    if (zbuf[d] >= thresh) {
      int pos = atomicAdd(&n_cand, 1);
      if (pos < CAND_MAX) cand[pos] = d;
    }
  }
  __syncthreads();

  if (tid == 0) {
    int    nc   = n_cand < CAND_MAX ? n_cand : CAND_MAX;
    double bz   = -1.0e300;
    int    bidx = 0x7fffffff;
    for (int i = 0; i < nc; ++i) {
      int d = cand[i];
      double z = (double)logits[base + d] + gumbel_d(jax_random_bits((uint32_t)(base + d)));
      if (z > bz || (z == bz && d < bidx)) { bz = z; bidx = d; }
    }
    idx_out[s] = bidx;
  }
}

// Rank-sort the 256 selected columns ascending (stable in s).
// sorted_col[r] = column with rank r; sorted_dst[r] = original s.
__global__ __launch_bounds__(256)
void sort_idx_kernel(const int* __restrict__ idx,
                     int* __restrict__ sorted_col,
                     int* __restrict__ sorted_dst) {
  __shared__ int cols[S_ROWS];
  const int s = threadIdx.x;
  const int c = idx[s];
  cols[s] = c;
  __syncthreads();
  int rank = 0;
#pragma unroll 8
  for (int t = 0; t < S_ROWS; ++t) {
    int ct = cols[t];
    rank += (ct < c) || (ct == c && t < s);
  }
  sorted_col[rank] = c;
  sorted_dst[rank] = s;
}

// Random gather with ascending per-wave addresses. 16 rows/block, all loads
// issued before stores (R3's MLP batching). Store scatters within the 1KB
// output row span (8 lines, merged in L2).
#define ROWS_PER_BLOCK 16
__global__ __launch_bounds__(256)
void gather_cols_kernel(const float* __restrict__ X,
                        const int* __restrict__ sorted_col,
                        const int* __restrict__ sorted_dst,
                        float* __restrict__ Y) {
  const int t   = threadIdx.x;            // rank 0..255 (ascending columns)
  const int col = sorted_col[t];          // ascending across lanes
  const int dst = sorted_dst[t];          // original output column
  const long b0 = (long)blockIdx.x * ROWS_PER_BLOCK;
  const float* xp = X + b0 * D_COLS + col;
  float v[ROWS_PER_BLOCK];
#pragma unroll
  for (int r = 0; r < ROWS_PER_BLOCK; ++r)
    v[r] = xp[(long)r * D_COLS];          // 16 ascending-address scattered loads
  float* yp = Y + b0 * S_ROWS + dst;
#pragma unroll
  for (int r = 0; r < ROWS_PER_BLOCK; ++r)
    yp[(long)r * S_ROWS] = v[r];          // scatter within 1KB span per row
}

extern "C" void kernel_launch(void* const* d_in, const int* in_sizes, int n_in,
                              void* d_out, int out_size, void* d_ws, size_t ws_size,
                              hipStream_t stream) {
  const float* X      = (const float*)d_in[0];   // [8192, 10000] fp32
  const float* logits = (const float*)d_in[1];   // [256, 10000] fp32
  float*       Y      = (float*)d_out;           // [8192, 256] fp32
  int* idx        = (int*)d_ws;                  // 256 ints
  int* sorted_col = idx + S_ROWS;                // 256 ints
  int* sorted_dst = sorted_col + S_ROWS;         // 256 ints

  argmax_gumbel_kernel<<<S_ROWS, ARGMAX_THREADS, 0, stream>>>(logits, idx);
  sort_idx_kernel<<<1, S_ROWS, 0, stream>>>(idx, sorted_col, sorted_dst);
  gather_cols_kernel<<<B_ROWS / ROWS_PER_BLOCK, 256, 0, stream>>>(X, sorted_col, sorted_dst, Y);
}

// Round 6
// 418.653 us; speedup vs baseline: 1.0912x; 1.0093x over previous
//
#include <hip/hip_runtime.h>
#include <stdint.h>

// ============================================================================
// ConcreteSelect: Y[b,s] = X[b, argmax_d(logits[s,d] + gumbel(key=42)[s,d])]
// Gumbel-softmax hard=True forward == one-hot column gather of X.
// PRNG: JAX threefry2x32, partitionable mode: x=(hi32(i),lo32(i)), bits=y0^y1.
// Bit-exact (absmax 0.0, rounds 1-5).
//
// FINAL (R6 = revert to R3, the session-best structure):
//   - argmax: float fast path (logf) + double re-verify of near-max candidates
//   - gather: random column gather, 16 batched loads in flight per thread,
//     nontemporal coalesced stores.
// Gather-side experiments all neutral or worse:
//   R3 MLP x2: neutral -> not request-rate-limited
//   R4 streaming scan of X: +40us regression -> stream costs more than it saves
//   R5 address-sorted requests: +5us -> not DRAM row-locality-limited
// Structural floor: ~183 MB of distinct random 128B lines at the measured
// ~2.3 TB/s random-line service rate (~80us) + ~330us harness reset window.
// ============================================================================

#define S_ROWS 256
#define D_COLS 10000
#define B_ROWS 8192

__device__ __forceinline__ void threefry2x32(uint32_t& x0, uint32_t& x1) {
  const uint32_t k0 = 0u;
  const uint32_t k1 = 42u;
  const uint32_t k2 = 0x1BD11BDAu ^ k0 ^ k1;
  x0 += k0; x1 += k1;
#define TFR(r) { x0 += x1; x1 = (x1 << (r)) | (x1 >> (32 - (r))); x1 ^= x0; }
  TFR(13) TFR(15) TFR(26) TFR(6)   x0 += k1; x1 += k2 + 1u;
  TFR(17) TFR(29) TFR(16) TFR(24)  x0 += k2; x1 += k0 + 2u;
  TFR(13) TFR(15) TFR(26) TFR(6)   x0 += k0; x1 += k1 + 3u;
  TFR(17) TFR(29) TFR(16) TFR(24)  x0 += k1; x1 += k2 + 4u;
  TFR(13) TFR(15) TFR(26) TFR(6)   x0 += k2; x1 += k0 + 5u;
#undef TFR
}

__device__ __forceinline__ uint32_t jax_random_bits(uint32_t i) {
  uint32_t x0 = 0u, x1 = i;
  threefry2x32(x0, x1);
  return x0 ^ x1;
}

__device__ __forceinline__ float uniform_from_bits(uint32_t bits) {
  uint32_t fb = (bits >> 9) | 0x3f800000u;     // [1,2)
  float u = __uint_as_float(fb) - 1.0f;        // [0,1)
  if (u <= 0.0f) u = 1.17549435e-38f;          // max(tiny, u)
  return u;
}

__device__ __forceinline__ float gumbel_f(uint32_t bits) {
  float u  = uniform_from_bits(bits);
  float nl = -logf(u);
  return -logf(nl);
}

__device__ __forceinline__ double gumbel_d(uint32_t bits) {
  float u = uniform_from_bits(bits);
  double lu = log((double)u);
  return -log(-lu);
}

#define ARGMAX_THREADS 1024
#define CAND_MAX 64

__global__ __launch_bounds__(ARGMAX_THREADS)
void argmax_gumbel_kernel(const float* __restrict__ logits, int* __restrict__ idx_out) {
  const int s   = blockIdx.x;      // 0..255
  const int tid = threadIdx.x;     // 0..1023
  const int base = s * D_COLS;

  __shared__ float zbuf[D_COLS];                 // 40 KB
  __shared__ float sv[ARGMAX_THREADS];           // 4 KB
  __shared__ int   si[ARGMAX_THREADS];           // 4 KB
  __shared__ int   n_cand;
  __shared__ int   cand[CAND_MAX];

  if (tid == 0) n_cand = 0;

  float best = -1.0e30f;
  int   bi   = 0;
  for (int d = tid; d < D_COLS; d += ARGMAX_THREADS) {
    uint32_t bits = jax_random_bits((uint32_t)(base + d));
    float z = logits[base + d] + gumbel_f(bits);
    zbuf[d] = z;
    if (z > best) { best = z; bi = d; }
  }
  sv[tid] = best; si[tid] = bi;
  __syncthreads();
  for (int off = ARGMAX_THREADS / 2; off > 0; off >>= 1) {
    if (tid < off) {
      float ov = sv[tid + off]; int oi = si[tid + off];
      if (ov > sv[tid] || (ov == sv[tid] && oi < si[tid])) { sv[tid] = ov; si[tid] = oi; }
    }
    __syncthreads();
  }

  // Double precision decides among all columns within EPS of the float max.
  const float thresh = sv[0] - 1.0e-3f;
  for (int d = tid; d < D_COLS; d += ARGMAX_THREADS) {
    if (zbuf[d] >= thresh) {
      int pos = atomicAdd(&n_cand, 1);
      if (pos < CAND_MAX) cand[pos] = d;
    }
  }
  __syncthreads();

  if (tid == 0) {
    int    nc   = n_cand < CAND_MAX ? n_cand : CAND_MAX;
    double bz   = -1.0e300;
    int    bidx = 0x7fffffff;
    for (int i = 0; i < nc; ++i) {
      int d = cand[i];
      double z = (double)logits[base + d] + gumbel_d(jax_random_bits((uint32_t)(base + d)));
      if (z > bz || (z == bz && d < bidx)) { bz = z; bidx = d; }
    }
    idx_out[s] = bidx;
  }
}

// 16 scattered loads in flight per thread before any store; nontemporal
// stores keep Y from displacing X lines in L2.
#define ROWS_PER_BLOCK 16
__global__ __launch_bounds__(256)
void gather_cols_kernel(const float* __restrict__ X,
                        const int* __restrict__ idx,
                        float* __restrict__ Y) {
  const int s   = threadIdx.x;           // output column 0..255
  const int col = idx[s];                // 1 KB broadcast, L2-hot
  const long b0 = (long)blockIdx.x * ROWS_PER_BLOCK;
  const float* xp = X + b0 * D_COLS + col;
  float v[ROWS_PER_BLOCK];
#pragma unroll
  for (int r = 0; r < ROWS_PER_BLOCK; ++r)
    v[r] = xp[(long)r * D_COLS];         // 16 independent scattered loads
  float* yp = Y + b0 * S_ROWS + s;
#pragma unroll
  for (int r = 0; r < ROWS_PER_BLOCK; ++r)
    __builtin_nontemporal_store(v[r], yp + (long)r * S_ROWS);  // coalesced
}

extern "C" void kernel_launch(void* const* d_in, const int* in_sizes, int n_in,
                              void* d_out, int out_size, void* d_ws, size_t ws_size,
                              hipStream_t stream) {
  const float* X      = (const float*)d_in[0];   // [8192, 10000] fp32
  const float* logits = (const float*)d_in[1];   // [256, 10000] fp32
  float*       Y      = (float*)d_out;           // [8192, 256] fp32
  int*         idx    = (int*)d_ws;              // 256 ints scratch

  argmax_gumbel_kernel<<<S_ROWS, ARGMAX_THREADS, 0, stream>>>(logits, idx);
  gather_cols_kernel<<<B_ROWS / ROWS_PER_BLOCK, 256, 0, stream>>>(X, idx, Y);
}